// Round 9
// baseline (73549.506 us; speedup 1.0000x reference)
//
#include <hip/hip_runtime.h>
#include <math.h>

// Problem dims: B=64, T=1000, D=H=E=512, V=5000, L=150
// All value-producing multiply-adds are EXPLICIT fmaf chains: FP bits are
// defined by source, independent of inlining context / wrapper structure.

// ws offsets (in floats)
#define OFF_SCORES 0u            // [64][1000]
#define OFF_PM     64000u        // [20][64]
#define OFF_PL     65280u        // [20][64]
#define OFF_PCTX   66560u        // [20][64][512]
#define OFF_XT     721920u       // xT[k<1024][b]
#define OFF_H      787456u       // h[b][k]
#define OFF_HT     820224u       // hT[k][b]
#define OFF_C      852992u       // c[b][k]
#define OFF_GP     885760u       // gp[6][2048][64]
#define OFF_LP     1672192u      // lp[2][5000][64]
#define WS_BAR     2332416u      // 2 ints: arrival count, generation

// d_out offsets (floats)
#define OUT_LOGITS 0ull
#define OUT_DECLP  48000000ull
#define OUT_PRED   48009600ull
#define OUT_ATTN   48019200ull

// ---------------------------------------------------------------------------
// Hand-rolled grid barrier: sense-reversing, device-scope atomics + fences.
// ---------------------------------------------------------------------------
__device__ __forceinline__ void gbar(int* __restrict__ bar, int nblk) {
  __syncthreads();
  if (threadIdx.x == 0) {
    __threadfence();  // release
    int g = __hip_atomic_load(&bar[1], __ATOMIC_RELAXED, __HIP_MEMORY_SCOPE_AGENT);
    int prev = __hip_atomic_fetch_add(&bar[0], 1, __ATOMIC_ACQ_REL, __HIP_MEMORY_SCOPE_AGENT);
    if (prev == nblk - 1) {
      __hip_atomic_store(&bar[0], 0, __ATOMIC_RELAXED, __HIP_MEMORY_SCOPE_AGENT);
      __hip_atomic_store(&bar[1], g + 1, __ATOMIC_RELEASE, __HIP_MEMORY_SCOPE_AGENT);
    } else {
      while (__hip_atomic_load(&bar[1], __ATOMIC_ACQUIRE, __HIP_MEMORY_SCOPE_AGENT) == g) {
        __builtin_amdgcn_s_sleep(2);
      }
    }
    __threadfence();  // acquire
  }
  __syncthreads();
}

// ---------------------------------------------------------------------------
// attention job: one (chunk c, batch b). 4 waves, online-softmax ctx partial.
// ---------------------------------------------------------------------------
__device__ void d_attn(int job, const float* __restrict__ enc,
                       const int* __restrict__ enc_len,
                       float* __restrict__ ws, float* __restrict__ smem) {
  const int c = job >> 6;
  const int b = job & 63;
  const int lane = threadIdx.x & 63;
  const int w = threadIdx.x >> 6;
  const int tid = threadIdx.x;
  float* sctx = smem;          // 2048
  float* sm   = smem + 2048;   // 4
  float* sl   = smem + 2052;   // 4

  const float* __restrict__ hb = ws + OFF_H + b * 512;
  const float4 h0 = *(const float4*)(hb + lane * 4);
  const float4 h1 = *(const float4*)(hb + 256 + lane * 4);

  float4 a0 = make_float4(0.f, 0.f, 0.f, 0.f);
  float4 a1 = make_float4(0.f, 0.f, 0.f, 0.f);
  float m = -3e38f, l = 0.f;
  const int len = enc_len[b];
  const int t0 = c * 50;
  float* __restrict__ scores = ws + OFF_SCORES + b * 1000;

  for (int t = t0 + w; t < t0 + 50; t += 4) {   // t wave-uniform
    const bool valid = (t < len);
    float s;
    float4 e0, e1;
    if (valid) {
      const float* __restrict__ ep = enc + ((size_t)b * 1000 + t) * 512;
      e0 = *(const float4*)(ep + lane * 4);
      e1 = *(const float4*)(ep + 256 + lane * 4);
      float p = e0.x * h0.x;
      p = fmaf(e0.y, h0.y, p);
      p = fmaf(e0.z, h0.z, p);
      p = fmaf(e0.w, h0.w, p);
      p = fmaf(e1.x, h1.x, p);
      p = fmaf(e1.y, h1.y, p);
      p = fmaf(e1.z, h1.z, p);
      p = fmaf(e1.w, h1.w, p);
      #pragma unroll
      for (int off = 1; off < 64; off <<= 1) p += __shfl_xor(p, off);
      s = p;
    } else {
      s = -1e9f;
      e0 = make_float4(0.f, 0.f, 0.f, 0.f);
      e1 = make_float4(0.f, 0.f, 0.f, 0.f);
    }
    if (lane == 0) scores[t] = s;
    if (valid) {
      const float mn = fmaxf(m, s);
      const float sc = expf(m - mn);
      const float wt = expf(s - mn);
      l = fmaf(l, sc, wt);
      m = mn;
      a0.x = fmaf(a0.x, sc, wt * e0.x); a0.y = fmaf(a0.y, sc, wt * e0.y);
      a0.z = fmaf(a0.z, sc, wt * e0.z); a0.w = fmaf(a0.w, sc, wt * e0.w);
      a1.x = fmaf(a1.x, sc, wt * e1.x); a1.y = fmaf(a1.y, sc, wt * e1.y);
      a1.z = fmaf(a1.z, sc, wt * e1.z); a1.w = fmaf(a1.w, sc, wt * e1.w);
    }
  }

  sctx[w * 512 + lane * 4 + 0] = a0.x;
  sctx[w * 512 + lane * 4 + 1] = a0.y;
  sctx[w * 512 + lane * 4 + 2] = a0.z;
  sctx[w * 512 + lane * 4 + 3] = a0.w;
  sctx[w * 512 + 256 + lane * 4 + 0] = a1.x;
  sctx[w * 512 + 256 + lane * 4 + 1] = a1.y;
  sctx[w * 512 + 256 + lane * 4 + 2] = a1.z;
  sctx[w * 512 + 256 + lane * 4 + 3] = a1.w;
  if (lane == 0) { sm[w] = m; sl[w] = l; }
  __syncthreads();

  const float M = fmaxf(fmaxf(sm[0], sm[1]), fmaxf(sm[2], sm[3]));
  const float f0 = expf(sm[0] - M), f1 = expf(sm[1] - M);
  const float f2 = expf(sm[2] - M), f3 = expf(sm[3] - M);
  float* __restrict__ pctx = ws + OFF_PCTX + ((size_t)c * 64 + b) * 512;
  for (int d = tid; d < 512; d += 256) {
    float v = sctx[d] * f0;
    v = fmaf(sctx[512 + d], f1, v);
    v = fmaf(sctx[1024 + d], f2, v);
    v = fmaf(sctx[1536 + d], f3, v);
    pctx[d] = v;
  }
  if (tid == 0) {
    ws[OFF_PM + c * 64 + b] = M;
    ws[OFF_PL + c * 64 + b] = fmaf(sl[3], f3, fmaf(sl[2], f2, fmaf(sl[1], f1, sl[0] * f0)));
  }
}

// ---------------------------------------------------------------------------
// combine job (one b): ctx combine -> xT, embedding -> xT, attn weights out.
// ---------------------------------------------------------------------------
__device__ void d_comb(int b, int t, const float* __restrict__ emb_table,
                       const int* __restrict__ dec_in,
                       float* __restrict__ ws, float* __restrict__ out,
                       float* __restrict__ smem) {
  const int tid = threadIdx.x;
  float* ef  = smem;        // 20
  float* spm = smem + 32;   // 20
  float* spl = smem + 64;   // 20
  float* sMS = smem + 96;   // 2

  if (tid < 20) {
    spm[tid] = ws[OFF_PM + tid * 64 + b];
    spl[tid] = ws[OFF_PL + tid * 64 + b];
  }
  __syncthreads();
  if (tid == 0) {
    float M = -3e38f;
    for (int c = 0; c < 20; ++c) M = fmaxf(M, spm[c]);
    float S = 0.f;
    for (int c = 0; c < 20; ++c) {
      const float e = expf(spm[c] - M);
      ef[c] = e;
      S = fmaf(spl[c], e, S);
    }
    sMS[0] = M; sMS[1] = S;
  }
  __syncthreads();
  const float M = sMS[0];
  const float invS = 1.f / sMS[1];

  for (int d = tid; d < 512; d += 256) {
    float acc = 0.f;
    #pragma unroll
    for (int c = 0; c < 20; ++c)
      acc = fmaf(ws[OFF_PCTX + ((size_t)c * 64 + b) * 512 + d], ef[c], acc);
    ws[OFF_XT + (size_t)(512 + d) * 64 + b] = acc * invS;
  }
  const int tok = dec_in[b * 150 + t];
  const float* __restrict__ er = emb_table + (size_t)tok * 512;
  for (int k = tid; k < 512; k += 256)
    ws[OFF_XT + (size_t)k * 64 + b] = (tok != 0) ? er[k] : 0.f;
  float* __restrict__ ao = out + OUT_ATTN + ((size_t)b * 150 + t) * 1000;
  const float* __restrict__ sc = ws + OFF_SCORES + b * 1000;
  for (int tt = tid; tt < 1000; tt += 256)
    ao[tt] = expf(sc[tt] - M) * invS;   // masked (-1e9) -> exactly 0
}

// ---------------------------------------------------------------------------
// lcomb job (one 64-wide v-chunk): combine ksplits + bias, write logits.
// ---------------------------------------------------------------------------
__device__ void d_lcomb(int vc, int t, const float* __restrict__ b_out,
                        float* __restrict__ ws, float* __restrict__ out,
                        float* __restrict__ smem) {
  const int v0 = vc * 64;
  const int NV = (5000 - v0 < 64) ? (5000 - v0) : 64;
  const int tid = threadIdx.x;
  float* Ls = smem;   // 64*65

  #pragma unroll
  for (int e = 0; e < 16; ++e) {
    const int idx = e * 256 + tid;
    const int v = idx >> 6, b = idx & 63;
    if (v < NV) {
      Ls[v * 65 + b] = ws[OFF_LP + (size_t)(v0 + v) * 64 + b]
                     + ws[OFF_LP + (size_t)(5000 + v0 + v) * 64 + b]
                     + b_out[v0 + v];
    }
  }
  __syncthreads();
  #pragma unroll
  for (int e = 0; e < 16; ++e) {
    const int idx = e * 256 + tid;
    const int v = idx & 63, b = idx >> 6;
    if (v < NV)
      out[OUT_LOGITS + ((size_t)b * 150 + t) * 5000 + v0 + v] = Ls[v * 65 + b];
  }
}

// ---------------------------------------------------------------------------
// lfinal job (one b, step tp): scan the WRITTEN logits row in d_out ->
// lse, first-occurrence argmax (np.argmax semantics), dec_lp, prediction.
// ---------------------------------------------------------------------------
__device__ void d_lfinal(int b, int tp, const int* __restrict__ dec_out,
                         float* __restrict__ out, float* __restrict__ smem) {
  const int tid = threadIdx.x;
  float* sv = smem;          // 256
  float* si = smem + 256;    // 256
  const float* __restrict__ lrow = out + OUT_LOGITS + ((size_t)b * 150 + tp) * 5000;

  float m = -3e38f;
  int bi = 0;
  for (int v = tid; v < 5000; v += 256) {
    const float val = lrow[v];
    if (val > m) { m = val; bi = v; }
  }
  sv[tid] = m;
  si[tid] = (float)bi;
  __syncthreads();
  for (int s = 128; s > 0; s >>= 1) {
    if (tid < s) {
      const float vo = sv[tid + s], io = si[tid + s];
      if (vo > sv[tid] || (vo == sv[tid] && io < si[tid])) { sv[tid] = vo; si[tid] = io; }
    }
    __syncthreads();
  }
  const float M = sv[0];
  const int amax = (int)si[0];
  __syncthreads();

  float s = 0.f;
  for (int v = tid; v < 5000; v += 256) s += expf(lrow[v] - M);
  sv[tid] = s;
  __syncthreads();
  for (int st = 128; st > 0; st >>= 1) {
    if (tid < st) sv[tid] += sv[tid + st];
    __syncthreads();
  }
  if (tid == 0) {
    const float lse = logf(sv[0]) + M;
    const int tok = dec_out[b * 150 + tp];
    out[OUT_DECLP + (size_t)b * 150 + tp] = lrow[tok] - lse;
    out[OUT_PRED  + (size_t)b * 150 + tp] = (float)amax;
  }
  __syncthreads();
}

// ---------------------------------------------------------------------------
// gates job: wave = 8 rows x 64 b x 256 k. 1536 wave-jobs over 384 block-jobs.
// ---------------------------------------------------------------------------
__device__ void d_gates(int job, const float* __restrict__ W_ih,
                        const float* __restrict__ W_hh, float* __restrict__ ws) {
  const int w = job * 4 + (threadIdx.x >> 6);  // 0..1535
  const int lane = threadIdx.x & 63;
  const int rg = w & 255;
  const int kc = w >> 8;                       // 0..5
  const int r0 = rg * 8;

  const float* __restrict__ Wp;
  const float* __restrict__ xp;
  int ld, kofs;
  if (kc < 4) { Wp = W_ih; ld = 1024; kofs = kc * 256; xp = ws + OFF_XT + (size_t)kofs * 64; }
  else        { Wp = W_hh; ld = 512;  kofs = (kc - 4) * 256; xp = ws + OFF_HT + (size_t)kofs * 64; }

  float acc[8] = {0.f, 0.f, 0.f, 0.f, 0.f, 0.f, 0.f, 0.f};
  for (int k = 0; k < 256; k += 4) {
    const float x0 = xp[(k + 0) * 64 + lane];
    const float x1 = xp[(k + 1) * 64 + lane];
    const float x2 = xp[(k + 2) * 64 + lane];
    const float x3 = xp[(k + 3) * 64 + lane];
    #pragma unroll
    for (int r = 0; r < 8; ++r) {
      const float4 wv = *(const float4*)(Wp + (size_t)(r0 + r) * ld + kofs + k);
      float a = acc[r];
      a = fmaf(wv.x, x0, a);
      a = fmaf(wv.y, x1, a);
      a = fmaf(wv.z, x2, a);
      a = fmaf(wv.w, x3, a);
      acc[r] = a;
    }
  }
  float* __restrict__ gp = ws + OFF_GP + ((size_t)kc * 2048 + r0) * 64;
  #pragma unroll
  for (int r = 0; r < 8; ++r) gp[r * 64 + lane] = acc[r];
}

// ---------------------------------------------------------------------------
// cell job (one of 128): combine gate partials + LSTM cell.
// ---------------------------------------------------------------------------
__device__ void d_cell(int job, const float* __restrict__ b_ih,
                       const float* __restrict__ b_hh, float* __restrict__ ws) {
  const int g = job * 256 + threadIdx.x;  // 0..32767
  const int b = g & 63;
  const int hi = g >> 6;
  float ai = b_ih[hi]        + b_hh[hi];
  float af = b_ih[hi + 512]  + b_hh[hi + 512];
  float ag = b_ih[hi + 1024] + b_hh[hi + 1024];
  float ao = b_ih[hi + 1536] + b_hh[hi + 1536];
  #pragma unroll
  for (int kc = 0; kc < 6; ++kc) {
    const float* __restrict__ gp = ws + OFF_GP + (size_t)kc * 2048 * 64;
    ai += gp[(hi       ) * 64 + b];
    af += gp[(hi +  512) * 64 + b];
    ag += gp[(hi + 1024) * 64 + b];
    ao += gp[(hi + 1536) * 64 + b];
  }
  const float cp = ws[OFF_C + b * 512 + hi];
  const float ig = 1.f / (1.f + expf(-ai));
  const float fg = 1.f / (1.f + expf(-af));
  const float gg = tanhf(ag);
  const float og = 1.f / (1.f + expf(-ao));
  const float c2 = fmaf(fg, cp, ig * gg);
  const float h2 = og * tanhf(c2);
  ws[OFF_C + b * 512 + hi] = c2;
  ws[OFF_H + b * 512 + hi] = h2;
  ws[OFF_HT + (size_t)hi * 64 + b] = h2;
}

// ---------------------------------------------------------------------------
// logits job: wave = 8 v-rows x 64 b x 256 k (ksplit 2). 313 block-jobs.
// ---------------------------------------------------------------------------
__device__ void d_logits(int job, const float* __restrict__ W_out,
                         float* __restrict__ ws) {
  const int w = job * 4 + (threadIdx.x >> 6);
  if (w >= 1250) return;
  const int lane = threadIdx.x & 63;
  const int vg = w % 625;
  const int ks = w / 625;
  const int v0 = vg * 8;
  const int k0 = ks * 256;
  const float* __restrict__ hT = ws + OFF_HT;
  float acc[8] = {0.f, 0.f, 0.f, 0.f, 0.f, 0.f, 0.f, 0.f};
  for (int k = k0; k < k0 + 256; k += 4) {
    const float x0 = hT[(k + 0) * 64 + lane];
    const float x1 = hT[(k + 1) * 64 + lane];
    const float x2 = hT[(k + 2) * 64 + lane];
    const float x3 = hT[(k + 3) * 64 + lane];
    #pragma unroll
    for (int r = 0; r < 8; ++r) {
      const float4 wv = *(const float4*)(W_out + (size_t)(v0 + r) * 512 + k);
      float a = acc[r];
      a = fmaf(wv.x, x0, a);
      a = fmaf(wv.y, x1, a);
      a = fmaf(wv.z, x2, a);
      a = fmaf(wv.w, x3, a);
      acc[r] = a;
    }
  }
  float* __restrict__ lp = ws + OFF_LP + ((size_t)ks * 5000 + v0) * 64;
  #pragma unroll
  for (int r = 0; r < 8; ++r) lp[r * 64 + lane] = acc[r];
}

// ---------------------------------------------------------------------------
// Persistent kernel with hand-rolled grid barrier. Per step: 4 barriers.
//   A: comb (t) ; lcomb (t-1)        [lcomb writes logits row t-1 to d_out]
//   B: gates (t) ; lfinal (t-1)
//   C: cell -> h_{t+1}
//   D: attention (t+1) ; logits (t)
// ---------------------------------------------------------------------------
__global__ __launch_bounds__(256, 2) void k_persist(
    const float* __restrict__ enc, const int* __restrict__ enc_len,
    const int* __restrict__ dec_in, const int* __restrict__ dec_out,
    const float* __restrict__ emb, const float* __restrict__ W_ih,
    const float* __restrict__ b_ih, const float* __restrict__ W_hh,
    const float* __restrict__ b_hh, const float* __restrict__ W_out,
    const float* __restrict__ b_out, float* __restrict__ ws,
    float* __restrict__ out) {
  __shared__ float smem[64 * 65];
  const int bid = blockIdx.x;
  const int nb = gridDim.x;
  int* bar = (int*)(ws + WS_BAR);

  // P0: attention for t=0 (h = 0)
  for (int job = bid; job < 1280; job += nb) {
    __syncthreads();
    d_attn(job, enc, enc_len, ws, smem);
  }
  gbar(bar, nb);

  for (int t = 0; t < 150; ++t) {
    {  // A
      const int nj = (t > 0) ? 143 : 64;
      for (int job = bid; job < nj; job += nb) {
        __syncthreads();
        if (job < 64) d_comb(job, t, emb, dec_in, ws, out, smem);
        else          d_lcomb(job - 64, t - 1, b_out, ws, out, smem);
      }
    }
    gbar(bar, nb);
    {  // B
      const int nj = (t > 0) ? 448 : 384;
      for (int job = bid; job < nj; job += nb) {
        __syncthreads();
        if (job < 384) d_gates(job, W_ih, W_hh, ws);
        else           d_lfinal(job - 384, t - 1, dec_out, out, smem);
      }
    }
    gbar(bar, nb);
    // C
    for (int job = bid; job < 128; job += nb) d_cell(job, b_ih, b_hh, ws);
    gbar(bar, nb);
    {  // D
      const int na = (t < 149) ? 1280 : 0;
      const int nj = na + 313;
      for (int job = bid; job < nj; job += nb) {
        __syncthreads();
        if (job < na) d_attn(job, enc, enc_len, ws, smem);
        else          d_logits(job - na, W_out, ws);
      }
    }
    gbar(bar, nb);
  }
  // tail: lcomb(149) -> barrier -> lfinal(149)
  for (int job = bid; job < 79; job += nb) {
    __syncthreads();
    d_lcomb(job, 149, b_out, ws, out, smem);
  }
  gbar(bar, nb);
  for (int job = bid; job < 64; job += nb) {
    __syncthreads();
    d_lfinal(job, 149, dec_out, out, smem);
  }
}

// ---------------------------------------------------------------------------
// Fallback wrappers (multi-kernel path, same pinned math)
// ---------------------------------------------------------------------------
__global__ __launch_bounds__(256) void k_attn_g(const float* __restrict__ enc,
                                                const int* __restrict__ enc_len,
                                                float* __restrict__ ws) {
  __shared__ float smem[2056];
  d_attn(blockIdx.x * 64 + blockIdx.y, enc, enc_len, ws, smem);
}
__global__ __launch_bounds__(256) void k_comb_g(const float* __restrict__ emb,
                                                const int* __restrict__ dec_in,
                                                const int* __restrict__ dec_out,
                                                float* __restrict__ ws,
                                                float* __restrict__ out, int t) {
  __shared__ float smem[512];
  if (t > 0) { d_lfinal(blockIdx.x, t - 1, dec_out, out, smem); __syncthreads(); }
  if (t < 150) d_comb(blockIdx.x, t, emb, dec_in, ws, out, smem);
}
__global__ __launch_bounds__(256) void k_gates_g(const float* __restrict__ W_ih,
                                                 const float* __restrict__ W_hh,
                                                 float* __restrict__ ws) {
  d_gates(blockIdx.x, W_ih, W_hh, ws);
}
__global__ __launch_bounds__(256) void k_cell_g(const float* __restrict__ b_ih,
                                                const float* __restrict__ b_hh,
                                                float* __restrict__ ws) {
  d_cell(blockIdx.x, b_ih, b_hh, ws);
}
__global__ __launch_bounds__(256) void k_logits_g(const float* __restrict__ W_out,
                                                  float* __restrict__ ws) {
  d_logits(blockIdx.x, W_out, ws);
}
__global__ __launch_bounds__(256) void k_lcomb_g(const float* __restrict__ b_out,
                                                 float* __restrict__ ws,
                                                 float* __restrict__ out, int t) {
  __shared__ float smem[64 * 65];
  d_lcomb(blockIdx.x, t, b_out, ws, out, smem);
}

// ---------------------------------------------------------------------------
extern "C" void kernel_launch(void* const* d_in, const int* in_sizes, int n_in,
                              void* d_out, int out_size, void* d_ws, size_t ws_size,
                              hipStream_t stream) {
  const float* enc     = (const float*)d_in[0];
  const int*   enc_len = (const int*)d_in[1];
  const int*   dec_in  = (const int*)d_in[2];
  const int*   dec_out = (const int*)d_in[3];
  const float* emb     = (const float*)d_in[4];
  const float* W_ih    = (const float*)d_in[5];
  const float* b_ih    = (const float*)d_in[6];
  const float* W_hh    = (const float*)d_in[7];
  const float* b_hh    = (const float*)d_in[8];
  const float* W_out   = (const float*)d_in[9];
  const float* b_out   = (const float*)d_in[10];
  float* out = (float*)d_out;
  float* ws  = (float*)d_ws;

  // zero h, hT, c (contiguous region) + barrier state
  hipMemsetAsync(ws + OFF_H, 0, (size_t)(3 * 32768) * sizeof(float), stream);
  hipMemsetAsync(ws + WS_BAR, 0, 2 * sizeof(int), stream);

  // size the persistent grid from queried occupancy (host-side, capture-safe)
  int dev = 0;
  (void)hipGetDevice(&dev);
  int numCU = 0, maxb = 0;
  (void)hipDeviceGetAttribute(&numCU, hipDeviceAttributeMultiprocessorCount, dev);
  hipError_t eo = hipOccupancyMaxActiveBlocksPerMultiprocessor(
      &maxb, (const void*)k_persist, 256, 0);
  if (eo != hipSuccess) maxb = 0;
  long nbl = (long)maxb * (long)(numCU > 0 ? numCU : 0);
  int nb = (nbl > 512) ? 512 : (int)nbl;

  bool done = false;
  if (nb >= 8) {
    void* args[] = {
      (void*)&enc, (void*)&enc_len, (void*)&dec_in, (void*)&dec_out, (void*)&emb,
      (void*)&W_ih, (void*)&b_ih, (void*)&W_hh, (void*)&b_hh, (void*)&W_out,
      (void*)&b_out, (void*)&ws, (void*)&out
    };
    hipError_t el = hipLaunchCooperativeKernel((const void*)k_persist, dim3(nb),
                                               dim3(256), args, 0, stream);
    if (el == hipSuccess) done = true;
    else (void)hipGetLastError();   // clear error state before fallback
  }

  if (!done) {
    for (int t = 0; t < 150; ++t) {
      k_attn_g  <<<dim3(20, 64), 256, 0, stream>>>(enc, enc_len, ws);
      k_comb_g  <<<64,  256, 0, stream>>>(emb, dec_in, dec_out, ws, out, t);
      k_gates_g <<<384, 256, 0, stream>>>(W_ih, W_hh, ws);
      k_cell_g  <<<128, 256, 0, stream>>>(b_ih, b_hh, ws);
      k_logits_g<<<313, 256, 0, stream>>>(W_out, ws);
      k_lcomb_g <<<79,  256, 0, stream>>>(b_out, ws, out, t);
    }
    k_comb_g<<<64, 256, 0, stream>>>(emb, dec_in, dec_out, ws, out, 150);
  }
}